// Round 2
// baseline (5050.310 us; speedup 1.0000x reference)
//
#include <hip/hip_runtime.h>
#include <math.h>

// NeuroSAT, MI355X. Round 2: single persistent cooperative kernel.
//  - All 23 message-passing steps in ONE kernel; LSTM states in registers,
//    per-node `out` in LDS. Only out_lit (3.3MB) and ch_cls (1.8MB) round-trip
//    global per step (flip reads / CSR gather cross block boundaries).
//  - Affine MLPs folded into LSTM input weights (MLP∘segment_sum commutes for
//    affine maps): kills yl/zl/zc/ycls buffers and ~25% of the FLOPs.
//  - 255 blocks x 512 threads (8 waves => 2 waves/SIMD for latency hiding).
//  - Grid sync: monotonic-counter barrier, device-scope atomics + threadfence.

#define NV2_   800
#define NC_    440
#define KK_    12
#define NPG_   1240
#define NLIT_  12800
#define NCLS_  7040
#define NE_    84480
#define NN_    19840
#define STEPS_ 23
#define LITB_  200     // literal blocks, 64 rows each
#define CLSB_  55      // clause blocks, 128 rows each (2 groups of 64)
#define NBLK_  255

__device__ __forceinline__ float sigmf(float x) { return 1.0f / (1.0f + __expf(-x)); }
__device__ __forceinline__ float tanhf_(float x) { return 1.0f - 2.0f / (__expf(2.0f * x) + 1.0f); }

// ---------------- setup kernels ----------------

// Collapse affine 3-layer MLPs. block 0: lm*->Wl,bl; 1: cm*->Wc,bc; 2: vote->Wv,bv.
__global__ __launch_bounds__(256) void collapse_k(
    const float* lm1, const float* lm1b, const float* lm2, const float* lm2b, const float* lm3, const float* lm3b,
    const float* cm1, const float* cm1b, const float* cm2, const float* cm2b, const float* cm3, const float* cm3b,
    const float* lv1, const float* lv1b, const float* lv2, const float* lv2b, const float* lv3, const float* lv3b,
    float* Wl, float* bl, float* Wc, float* bc, float* Wv, float* bv)
{
    __shared__ float T[4096];
    __shared__ float ub[64];
    __shared__ float t3[64];
    int r = blockIdx.x, t = threadIdx.x;
    if (r < 2) {
        const float* w1 = r ? cm1 : lm1; const float* b1 = r ? cm1b : lm1b;
        const float* w2 = r ? cm2 : lm2; const float* b2 = r ? cm2b : lm2b;
        const float* w3 = r ? cm3 : lm3; const float* b3 = r ? cm3b : lm3b;
        float* W = r ? Wc : Wl;  float* bb = r ? bc : bl;
        for (int idx = t; idx < 4096; idx += 256) {
            int i = idx >> 6, j = idx & 63;
            float s = 0.f;
            for (int k = 0; k < 64; ++k) s += w1[i * 64 + k] * w2[k * 64 + j];
            T[idx] = s;
        }
        if (t < 64) {
            float s = 0.f;
            for (int k = 0; k < 64; ++k) s += b1[k] * w2[k * 64 + t];
            ub[t] = s + b2[t];
        }
        __syncthreads();
        for (int idx = t; idx < 4096; idx += 256) {
            int i = idx >> 6, j = idx & 63;
            float s = 0.f;
            for (int k = 0; k < 64; ++k) s += T[i * 64 + k] * w3[k * 64 + j];
            W[idx] = s;
        }
        if (t < 64) {
            float s = 0.f;
            for (int k = 0; k < 64; ++k) s += ub[k] * w3[k * 64 + t];
            bb[t] = s + b3[t];
        }
    } else {
        if (t < 64) {
            float s = 0.f;
            for (int j = 0; j < 64; ++j) s += lv2[t * 64 + j] * lv3[j];
            t3[t] = s;
            float s2 = 0.f;
            for (int k = 0; k < 64; ++k) s2 += lv1b[k] * lv2[k * 64 + t];
            ub[t] = s2 + lv2b[t];
        }
        __syncthreads();
        if (t < 64) {
            float s = 0.f;
            for (int k = 0; k < 64; ++k) s += lv1[t * 64 + k] * t3[k];
            Wv[t] = s;
        }
        if (t == 0) {
            float s = 0.f;
            for (int j = 0; j < 64; ++j) s += ub[j] * lv3[j];
            bv[0] = s + lv3b[0];
        }
    }
}

// Fold collapsed MLPs into the LSTM input weights.
// block 0: Wfl = Wc @ lwih[64:128], bfl = bc @ lwih[64:128], Bl = lbih+lbhh
// block 1: Wfc = Wl @ cwih,         Bc  = cbih+cbhh + 13*(bl @ cwih)
__global__ __launch_bounds__(256) void fold_k(
    const float* Wl, const float* bl, const float* Wc, const float* bc,
    const float* lwih, const float* lbih, const float* lbhh,
    const float* cwih, const float* cbih, const float* cbhh,
    float* Wfl, float* bfl, float* Bl, float* Wfc, float* Bc)
{
    int j = threadIdx.x;  // 0..255
    if (blockIdx.x == 0) {
        for (int i = 0; i < 64; ++i) {
            float s = 0.f;
            for (int m = 0; m < 64; ++m) s += Wc[i * 64 + m] * lwih[(64 + m) * 256 + j];
            Wfl[i * 256 + j] = s;
        }
        float s = 0.f;
        for (int m = 0; m < 64; ++m) s += bc[m] * lwih[(64 + m) * 256 + j];
        bfl[j] = s;
        Bl[j] = lbih[j] + lbhh[j];
    } else {
        for (int i = 0; i < 64; ++i) {
            float s = 0.f;
            for (int m = 0; m < 64; ++m) s += Wl[i * 64 + m] * cwih[m * 256 + j];
            Wfc[i * 256 + j] = s;
        }
        float s = 0.f;
        for (int m = 0; m < 64; ++m) s += bl[m] * cwih[m * 256 + j];
        Bc[j] = cbih[j] + cbhh[j] + 13.f * s;
    }
}

__global__ __launch_bounds__(256) void init_k(
    const float* x, const float* liw, const float* lib, const float* ciw, const float* cib,
    float* out0, float* outc)
{
    int t = blockIdx.x * 256 + threadIdx.x;
    if (t >= NN_ * 64) return;
    int node = t >> 6, j = t & 63;
    int b = node / NPG_;
    int i = node - b * NPG_;
    float x0 = x[node * 2 + 0], x1 = x[node * 2 + 1];
    if (i < NV2_) out0[(size_t)(b * NV2_ + i) * 64 + j] = x0 * liw[j] + x1 * liw[64 + j] + lib[j];
    else          outc[(size_t)(b * NC_ + (i - NV2_)) * 64 + j] = x0 * ciw[j] + x1 * ciw[64 + j] + cib[j];
}

__global__ __launch_bounds__(256) void econv_k(const int* ei, int* llits, int* cnt)
{
    int e = blockIdx.x * 256 + threadIdx.x;
    if (e >= NE_) return;
    int g = ei[e];
    int b = g / NPG_;
    int L = b * NV2_ + (g - b * NPG_);
    llits[e] = L;
    atomicAdd(cnt + L, 1);
}

__global__ __launch_bounds__(1024) void scan_k(const int* cnt, int* rowptr, int* cursor)
{
    __shared__ int sums[1024];
    int t = threadIdx.x;
    int i0 = t * 13;
    int i1 = i0 + 13; if (i1 > NLIT_) i1 = NLIT_; if (i0 > NLIT_) i0 = NLIT_;
    int s = 0;
    for (int i = i0; i < i1; ++i) s += cnt[i];
    sums[t] = s;
    __syncthreads();
    for (int off = 1; off < 1024; off <<= 1) {
        int v = (t >= off) ? sums[t - off] : 0;
        __syncthreads();
        sums[t] += v;
        __syncthreads();
    }
    int run = sums[t] - s;
    for (int i = i0; i < i1; ++i) { rowptr[i] = run; cursor[i] = run; run += cnt[i]; }
    if (t == 1023) rowptr[NLIT_] = sums[1023];
}

__global__ __launch_bounds__(256) void fill_k(const int* llits, int* cursor, int* col)
{
    int e = blockIdx.x * 256 + threadIdx.x;
    if (e >= NE_) return;
    int pos = atomicAdd(cursor + llits[e], 1);
    col[pos] = e / KK_;
}

// ---------------- persistent fused kernel ----------------

struct KArgs {
    float* out_g; float* outc0; float* chg;
    const int* llits; const int* rowptr; const int* col;
    const float* Wfl; const float* bfl; const float* Bl;
    const float* Wfc; const float* Bc;
    const float* lwih; const float* lwhh;
    const float* cwhh;
    const float* Wv; const float* bv;
    float* vout;
    int* bar;
};

__device__ __forceinline__ void gsync(int* bar, int target)
{
    __syncthreads();
    if (threadIdx.x == 0) {
        __threadfence();
        __hip_atomic_fetch_add(bar, 1, __ATOMIC_RELAXED, __HIP_MEMORY_SCOPE_AGENT);
        while (__hip_atomic_load(bar, __ATOMIC_RELAXED, __HIP_MEMORY_SCOPE_AGENT) < target * NBLK_) {
            __builtin_amdgcn_s_sleep(2);
        }
        __threadfence();
    }
    __syncthreads();
}

// acc[t*8+q] += sum_k Ls[lane*65+k] * W[k*256 + t*64 + ucb + q]
__device__ __forceinline__ void gate_lds(const float* Ls, int lane, const float* W, int ucb, float* acc)
{
#pragma unroll 4
    for (int k = 0; k < 64; ++k) {
        float u = Ls[lane * 65 + k];
        const float* wr = W + k * 256 + ucb;
#pragma unroll
        for (int t = 0; t < 4; ++t)
#pragma unroll
            for (int q = 0; q < 8; ++q) acc[t * 8 + q] += u * wr[t * 64 + q];
    }
}

// acc += row(g) @ W, row read as float4 from global
__device__ __forceinline__ void gate_g4(const float* g, const float* W, int ucb, float* acc)
{
    const float4* p = (const float4*)g;
#pragma unroll 2
    for (int k4 = 0; k4 < 16; ++k4) {
        float4 v = p[k4];
        const float* w0 = W + (k4 * 4 + 0) * 256 + ucb;
        const float* w1 = W + (k4 * 4 + 1) * 256 + ucb;
        const float* w2 = W + (k4 * 4 + 2) * 256 + ucb;
        const float* w3 = W + (k4 * 4 + 3) * 256 + ucb;
#pragma unroll
        for (int t = 0; t < 4; ++t)
#pragma unroll
            for (int q = 0; q < 8; ++q) {
                acc[t * 8 + q] += v.x * w0[t * 64 + q];
                acc[t * 8 + q] += v.y * w1[t * 64 + q];
                acc[t * 8 + q] += v.z * w2[t * 64 + q];
                acc[t * 8 + q] += v.w * w3[t * 64 + q];
            }
    }
}

__device__ __forceinline__ void cell8(const float* acc, float* c_r, float* h2)
{
#pragma unroll
    for (int q = 0; q < 8; ++q) {
        float iv = sigmf(acc[q]);
        float fv = sigmf(acc[8 + q]);
        float gv = tanhf_(acc[16 + q]);
        float ov = sigmf(acc[24 + q]);
        float c2 = fv * c_r[q] + iv * gv;
        c_r[q] = c2;
        h2[q] = ov * tanhf_(c2);
    }
}

__global__ __launch_bounds__(512) void fused_k(KArgs a)
{
    __shared__ float A0[65 * 64];
    __shared__ float A1[65 * 64];
    __shared__ float A2[65 * 64];
    const int tid = threadIdx.x;
    const int lane = tid & 63;
    const int wv = __builtin_amdgcn_readfirstlane(tid >> 6);   // 0..7
    const int ucb = wv * 8;

    if (blockIdx.x < LITB_) {
        // ---------------- literal block: 64 rows ----------------
        const int Lb = blockIdx.x * 64;
        const int row = Lb + lane;
#pragma unroll
        for (int s0 = 0; s0 < 8; ++s0) {
            int s = wv * 8 + s0;
            A0[s * 65 + lane] = a.out_g[(size_t)(Lb + s) * 64 + lane];
        }
        float lc_r[8];
#pragma unroll
        for (int q = 0; q < 8; ++q) lc_r[q] = 0.f;
        const int pi = row % NV2_;
        const int fl = row - pi + ((pi < 400) ? pi + 400 : pi - 400);
        const int deg = a.rowptr[row + 1] - a.rowptr[row];
        const float degf = 1.f + (float)deg;
        int sn = 0;
        __syncthreads();
        for (int step = 0; step < STEPS_; ++step) {
            gsync(a.bar, ++sn);     // S1: out_g(step) visible everywhere
            // slot1 (overlaps clause work): A1 <- own out; partial gates
#pragma unroll
            for (int s0 = 0; s0 < 8; ++s0) {
                int s = wv * 8 + s0;
                A1[s * 65 + lane] = A0[s * 65 + lane];
            }
            float acc[32];
#pragma unroll
            for (int t = 0; t < 4; ++t)
#pragma unroll
                for (int q = 0; q < 8; ++q)
                    acc[t * 8 + q] = a.Bl[t * 64 + ucb + q] + degf * a.bfl[t * 64 + ucb + q];
            gate_g4(a.out_g + (size_t)fl * 64, a.lwih, ucb, acc);   // out[flip] @ wih[0:64]
            if (step) gate_lds(A0, lane, a.lwhh, ucb, acc);         // lh @ whh  (lh == A0)
            gsync(a.bar, ++sn);     // S2: chg(step) visible
            // slot2: gather clause h into A1 (c_msg raw), folded GEMM, cell
            for (int s0 = 0; s0 < 8; ++s0) {
                int s = wv * 8 + s0;
                int l = Lb + s;
                int e = a.rowptr[l], r1 = a.rowptr[l + 1];
                float v = A1[s * 65 + lane];
                for (; e + 4 <= r1; e += 4) {
                    int c0 = a.col[e], c1 = a.col[e + 1], c2 = a.col[e + 2], c3 = a.col[e + 3];
                    float t0 = a.chg[(size_t)c0 * 64 + lane];
                    float t1 = a.chg[(size_t)c1 * 64 + lane];
                    float t2 = a.chg[(size_t)c2 * 64 + lane];
                    float t3 = a.chg[(size_t)c3 * 64 + lane];
                    v += t0 + t1 + t2 + t3;
                }
                for (; e < r1; ++e) v += a.chg[(size_t)a.col[e] * 64 + lane];
                A1[s * 65 + lane] = v;
            }
            __syncthreads();
            gate_lds(A1, lane, a.Wfl, ucb, acc);                    // folded c_msg part
            float h2[8];
            cell8(acc, lc_r, h2);
            __syncthreads();        // all A0/A1 reads complete before overwrite
#pragma unroll
            for (int q = 0; q < 8; ++q) {
                A0[lane * 65 + ucb + q] = h2[q];
                a.out_g[(size_t)row * 64 + ucb + q] = h2[q];
            }
            if (step == STEPS_ - 1) {
                float p = 0.f;
#pragma unroll
                for (int q = 0; q < 8; ++q) p += h2[q] * a.Wv[ucb + q];
                __syncthreads();
                A1[wv * 64 + lane] = p;
                __syncthreads();
                if (wv == 0) {
                    float v = a.bv[0];
#pragma unroll
                    for (int w = 0; w < 8; ++w) v += A1[w * 64 + lane];
                    int b = row / NV2_;
                    a.vout[b * NPG_ + (row - b * NV2_)] = v;
                }
            }
        }
    } else {
        // ---------------- clause block: 128 rows (2 groups) ----------------
        const int Cb = (blockIdx.x - LITB_) * 128;
        for (int g = 0; g < 2; ++g) {
            float* LM = g ? A1 : A0;
#pragma unroll
            for (int s0 = 0; s0 < 8; ++s0) {
                int s = wv * 8 + s0;
                LM[s * 65 + lane] = a.outc0[(size_t)(Cb + g * 64 + s) * 64 + lane];
            }
        }
        float cc_r[2][8], ch_r[2][8];
#pragma unroll
        for (int g = 0; g < 2; ++g)
#pragma unroll
            for (int q = 0; q < 8; ++q) { cc_r[g][q] = 0.f; ch_r[g][q] = 0.f; }
        int sn = 0;
        __syncthreads();
        for (int step = 0; step < STEPS_; ++step) {
            gsync(a.bar, ++sn);     // S1: out_g(step) visible
            for (int g = 0; g < 2; ++g) {
                float* LM = g ? A1 : A0;
                if (step) {
#pragma unroll
                    for (int q = 0; q < 8; ++q) A2[lane * 65 + ucb + q] = ch_r[g][q];
                }
                // gather: LM (holds clause out) += sum of 12 literal outs
                for (int s0 = 0; s0 < 8; ++s0) {
                    int s = wv * 8 + s0;
                    int c = Cb + g * 64 + s;
                    const int* lp = a.llits + c * KK_;
                    float v = LM[s * 65 + lane];
#pragma unroll
                    for (int k = 0; k < KK_; ++k) v += a.out_g[(size_t)lp[k] * 64 + lane];
                    LM[s * 65 + lane] = v;
                }
                __syncthreads();
                float acc[32];
#pragma unroll
                for (int t = 0; t < 4; ++t)
#pragma unroll
                    for (int q = 0; q < 8; ++q) acc[t * 8 + q] = a.Bc[t * 64 + ucb + q];
                gate_lds(LM, lane, a.Wfc, ucb, acc);                // folded l_msg part
                if (step) gate_lds(A2, lane, a.cwhh, ucb, acc);     // ch @ whh
                float h2[8];
                cell8(acc, cc_r[g], h2);
#pragma unroll
                for (int q = 0; q < 8; ++q) ch_r[g][q] = h2[q];
                __syncthreads();    // LM/A2 reads complete
                int c = Cb + g * 64 + lane;
#pragma unroll
                for (int q = 0; q < 8; ++q) {
                    LM[lane * 65 + ucb + q] = h2[q];                // LM = clause out (next)
                    a.chg[(size_t)c * 64 + ucb + q] = h2[q];
                }
            }
            gsync(a.bar, ++sn);     // S2 (lit blocks now consume chg)
        }
    }
}

// ---------------- host ----------------

extern "C" void kernel_launch(void* const* d_in, const int* in_sizes, int n_in,
                              void* d_out, int out_size, void* d_ws, size_t ws_size,
                              hipStream_t stream)
{
    (void)in_sizes; (void)n_in; (void)out_size; (void)ws_size;
    const float* x    = (const float*)d_in[0];
    const int*   ei   = (const int*)d_in[2];
    const float* liw  = (const float*)d_in[4];
    const float* lib  = (const float*)d_in[5];
    const float* ciw  = (const float*)d_in[6];
    const float* cib  = (const float*)d_in[7];
    const float* lm1  = (const float*)d_in[8];
    const float* lm1b = (const float*)d_in[9];
    const float* lm2  = (const float*)d_in[10];
    const float* lm2b = (const float*)d_in[11];
    const float* lm3  = (const float*)d_in[12];
    const float* lm3b = (const float*)d_in[13];
    const float* cm1  = (const float*)d_in[14];
    const float* cm1b = (const float*)d_in[15];
    const float* cm2  = (const float*)d_in[16];
    const float* cm2b = (const float*)d_in[17];
    const float* cm3  = (const float*)d_in[18];
    const float* cm3b = (const float*)d_in[19];
    const float* lu_wih = (const float*)d_in[20];
    const float* lu_whh = (const float*)d_in[21];
    const float* lu_bih = (const float*)d_in[22];
    const float* lu_bhh = (const float*)d_in[23];
    const float* cu_wih = (const float*)d_in[24];
    const float* cu_whh = (const float*)d_in[25];
    const float* cu_bih = (const float*)d_in[26];
    const float* cu_bhh = (const float*)d_in[27];
    const float* lv1  = (const float*)d_in[28];
    const float* lv1b = (const float*)d_in[29];
    const float* lv2  = (const float*)d_in[30];
    const float* lv2b = (const float*)d_in[31];
    const float* lv3  = (const float*)d_in[32];
    const float* lv3b = (const float*)d_in[33];

    float* F = (float*)d_ws;
    size_t o = 0;
    auto A = [&](size_t n) { float* p = F + o; o += n; return p; };
    float* out_g = A((size_t)NLIT_ * 64);
    float* outc0 = A((size_t)NCLS_ * 64);
    float* chg   = A((size_t)NCLS_ * 64);
    float* Wl    = A(4096);
    float* Wc    = A(4096);
    float* bl    = A(64);
    float* bc    = A(64);
    float* Wv    = A(64);
    float* bv    = A(16);
    float* Wfl   = A(64 * 256);
    float* bfl   = A(256);
    float* Bl    = A(256);
    float* Wfc   = A(64 * 256);
    float* Bc    = A(256);
    int* I = (int*)(F + o);
    int* llits  = I; I += NE_;
    int* rowptr = I; I += 12804;
    int* cursor = I; I += NLIT_;
    int* colA   = I; I += NE_;
    int* cnt    = I; I += NLIT_;
    int* bar    = I; I += 16;

    hipMemsetAsync(cnt, 0, NLIT_ * sizeof(int), stream);
    hipMemsetAsync(bar, 0, sizeof(int), stream);
    hipMemsetAsync(d_out, 0, (size_t)NN_ * sizeof(float), stream);

    collapse_k<<<3, 256, 0, stream>>>(lm1, lm1b, lm2, lm2b, lm3, lm3b,
                                      cm1, cm1b, cm2, cm2b, cm3, cm3b,
                                      lv1, lv1b, lv2, lv2b, lv3, lv3b,
                                      Wl, bl, Wc, bc, Wv, bv);
    fold_k<<<2, 256, 0, stream>>>(Wl, bl, Wc, bc,
                                  lu_wih, lu_bih, lu_bhh,
                                  cu_wih, cu_bih, cu_bhh,
                                  Wfl, bfl, Bl, Wfc, Bc);
    init_k<<<(NN_ * 64 + 255) / 256, 256, 0, stream>>>(x, liw, lib, ciw, cib, out_g, outc0);
    econv_k<<<NE_ / 256, 256, 0, stream>>>(ei, llits, cnt);
    scan_k<<<1, 1024, 0, stream>>>(cnt, rowptr, cursor);
    fill_k<<<NE_ / 256, 256, 0, stream>>>(llits, cursor, colA);

    KArgs ka;
    ka.out_g = out_g; ka.outc0 = outc0; ka.chg = chg;
    ka.llits = llits; ka.rowptr = rowptr; ka.col = colA;
    ka.Wfl = Wfl; ka.bfl = bfl; ka.Bl = Bl; ka.Wfc = Wfc; ka.Bc = Bc;
    ka.lwih = lu_wih; ka.lwhh = lu_whh; ka.cwhh = cu_whh;
    ka.Wv = Wv; ka.bv = bv;
    ka.vout = (float*)d_out;
    ka.bar = bar;

    void* params[] = { &ka };
    hipError_t err = hipLaunchCooperativeKernel((void*)fused_k, dim3(NBLK_), dim3(512),
                                                params, 0, stream);
    if (err != hipSuccess) {
        // residency is still guaranteed in practice (255 blocks <= 256 CUs, 8 waves/CU)
        fused_k<<<NBLK_, 512, 0, stream>>>(ka);
    }
}

// Round 3
// 2551.135 us; speedup vs baseline: 1.9796x; 1.9796x over previous
//
#include <hip/hip_runtime.h>
#include <math.h>

// NeuroSAT, MI355X. Round 3: persistent cooperative kernel with LDS-staged
// weights (the round-2 stall was L1-thrashed weight re-reads from L2 every
// step: VALUBusy 6.6%).
//  - 255 blocks x 1024 threads (4 waves/SIMD). Lit blocks split by unit-half
//    so each block's weight slice (3 x 64x128 fp32 = 96 KB) fits LDS.
//  - Literal rows stored pair-interleaved (sigma(pi)=2pi / 2(pi-400)+1) so the
//    flip row is lr^1 in the block's own LDS buffer -> no strided global reads.
//  - Clause blocks: full 64x256 weight set (128 KB) in LDS; they skip the S2
//    wait and precompute next step's ch@whh in the S2->S1 window.
//  - Affine MLPs folded into LSTM input weights (as round 2).

#define NV2_   800
#define NC_    440
#define KK_    12
#define NPG_   1240
#define NLIT_  12800
#define NCLS_  7040
#define NE_    84480
#define NN_    19840
#define STEPS_ 23
#define LITB_  200      // 100 row-groups x 2 unit-halves
#define NBLK_  255
#define SMEM_BYTES 148480

__device__ __forceinline__ float sigmf(float x) { return 1.0f / (1.0f + __expf(-x)); }
__device__ __forceinline__ float tanhf_(float x) { return 1.0f - 2.0f / (__expf(2.0f * x) + 1.0f); }

// ---------------- setup kernels ----------------

__global__ __launch_bounds__(256) void collapse_k(
    const float* lm1, const float* lm1b, const float* lm2, const float* lm2b, const float* lm3, const float* lm3b,
    const float* cm1, const float* cm1b, const float* cm2, const float* cm2b, const float* cm3, const float* cm3b,
    const float* lv1, const float* lv1b, const float* lv2, const float* lv2b, const float* lv3, const float* lv3b,
    float* Wl, float* bl, float* Wc, float* bc, float* Wv, float* bv)
{
    __shared__ float T[4096];
    __shared__ float ub[64];
    __shared__ float t3[64];
    int r = blockIdx.x, t = threadIdx.x;
    if (r < 2) {
        const float* w1 = r ? cm1 : lm1; const float* b1 = r ? cm1b : lm1b;
        const float* w2 = r ? cm2 : lm2; const float* b2 = r ? cm2b : lm2b;
        const float* w3 = r ? cm3 : lm3; const float* b3 = r ? cm3b : lm3b;
        float* W = r ? Wc : Wl;  float* bb = r ? bc : bl;
        for (int idx = t; idx < 4096; idx += 256) {
            int i = idx >> 6, j = idx & 63;
            float s = 0.f;
            for (int k = 0; k < 64; ++k) s += w1[i * 64 + k] * w2[k * 64 + j];
            T[idx] = s;
        }
        if (t < 64) {
            float s = 0.f;
            for (int k = 0; k < 64; ++k) s += b1[k] * w2[k * 64 + t];
            ub[t] = s + b2[t];
        }
        __syncthreads();
        for (int idx = t; idx < 4096; idx += 256) {
            int i = idx >> 6, j = idx & 63;
            float s = 0.f;
            for (int k = 0; k < 64; ++k) s += T[i * 64 + k] * w3[k * 64 + j];
            W[idx] = s;
        }
        if (t < 64) {
            float s = 0.f;
            for (int k = 0; k < 64; ++k) s += ub[k] * w3[k * 64 + t];
            bb[t] = s + b3[t];
        }
    } else {
        if (t < 64) {
            float s = 0.f;
            for (int j = 0; j < 64; ++j) s += lv2[t * 64 + j] * lv3[j];
            t3[t] = s;
            float s2 = 0.f;
            for (int k = 0; k < 64; ++k) s2 += lv1b[k] * lv2[k * 64 + t];
            ub[t] = s2 + lv2b[t];
        }
        __syncthreads();
        if (t < 64) {
            float s = 0.f;
            for (int k = 0; k < 64; ++k) s += lv1[t * 64 + k] * t3[k];
            Wv[t] = s;
        }
        if (t == 0) {
            float s = 0.f;
            for (int j = 0; j < 64; ++j) s += ub[j] * lv3[j];
            bv[0] = s + lv3b[0];
        }
    }
}

// Wfl = Wc @ lwih[64:128]; bfl = bc @ lwih[64:128]; Bl = lbih+lbhh
// Wfc = Wl @ cwih;         Bc  = cbih+cbhh + 13*(bl @ cwih)
__global__ __launch_bounds__(256) void fold_k(
    const float* Wl, const float* bl, const float* Wc, const float* bc,
    const float* lwih, const float* lbih, const float* lbhh,
    const float* cwih, const float* cbih, const float* cbhh,
    float* Wfl, float* bfl, float* Bl, float* Wfc, float* Bc)
{
    int j = threadIdx.x;
    if (blockIdx.x == 0) {
        for (int i = 0; i < 64; ++i) {
            float s = 0.f;
            for (int m = 0; m < 64; ++m) s += Wc[i * 64 + m] * lwih[(64 + m) * 256 + j];
            Wfl[i * 256 + j] = s;
        }
        float s = 0.f;
        for (int m = 0; m < 64; ++m) s += bc[m] * lwih[(64 + m) * 256 + j];
        bfl[j] = s;
        Bl[j] = lbih[j] + lbhh[j];
    } else {
        for (int i = 0; i < 64; ++i) {
            float s = 0.f;
            for (int m = 0; m < 64; ++m) s += Wl[i * 64 + m] * cwih[m * 256 + j];
            Wfc[i * 256 + j] = s;
        }
        float s = 0.f;
        for (int m = 0; m < 64; ++m) s += bl[m] * cwih[m * 256 + j];
        Bc[j] = cbih[j] + cbhh[j] + 13.f * s;
    }
}

// literal rows pair-interleaved: sigma(i) = i<400 ? 2i : 2(i-400)+1
__global__ __launch_bounds__(256) void init_k(
    const float* x, const float* liw, const float* lib, const float* ciw, const float* cib,
    float* out0, float* outc)
{
    int t = blockIdx.x * 256 + threadIdx.x;
    if (t >= NN_ * 64) return;
    int node = t >> 6, j = t & 63;
    int b = node / NPG_;
    int i = node - b * NPG_;
    float x0 = x[node * 2 + 0], x1 = x[node * 2 + 1];
    if (i < NV2_) {
        int sp = (i < 400) ? 2 * i : 2 * (i - 400) + 1;
        out0[(size_t)(b * NV2_ + sp) * 64 + j] = x0 * liw[j] + x1 * liw[64 + j] + lib[j];
    } else {
        outc[(size_t)(b * NC_ + (i - NV2_)) * 64 + j] = x0 * ciw[j] + x1 * ciw[64 + j] + cib[j];
    }
}

__global__ __launch_bounds__(256) void econv_k(const int* ei, int* llits, int* cnt)
{
    int e = blockIdx.x * 256 + threadIdx.x;
    if (e >= NE_) return;
    int g = ei[e];
    int b = g / NPG_;
    int i = g - b * NPG_;
    int sp = (i < 400) ? 2 * i : 2 * (i - 400) + 1;
    int L = b * NV2_ + sp;
    llits[e] = L;
    atomicAdd(cnt + L, 1);
}

__global__ __launch_bounds__(1024) void scan_k(const int* cnt, int* rowptr, int* cursor)
{
    __shared__ int sums[1024];
    int t = threadIdx.x;
    int i0 = t * 13;
    int i1 = i0 + 13; if (i1 > NLIT_) i1 = NLIT_; if (i0 > NLIT_) i0 = NLIT_;
    int s = 0;
    for (int i = i0; i < i1; ++i) s += cnt[i];
    sums[t] = s;
    __syncthreads();
    for (int off = 1; off < 1024; off <<= 1) {
        int v = (t >= off) ? sums[t - off] : 0;
        __syncthreads();
        sums[t] += v;
        __syncthreads();
    }
    int run = sums[t] - s;
    for (int i = i0; i < i1; ++i) { rowptr[i] = run; cursor[i] = run; run += cnt[i]; }
    if (t == 1023) rowptr[NLIT_] = sums[1023];
}

__global__ __launch_bounds__(256) void fill_k(const int* llits, int* cursor, int* col)
{
    int e = blockIdx.x * 256 + threadIdx.x;
    if (e >= NE_) return;
    int pos = atomicAdd(cursor + llits[e], 1);
    col[pos] = e / KK_;
}

// ---------------- persistent fused kernel ----------------

struct KArgs {
    float* out_g; float* outc0; float* chg;
    const int* llits; const int* rowptr; const int* col;
    const float* Wfl; const float* bfl; const float* Bl;
    const float* Wfc; const float* Bc;
    const float* lwih; const float* lwhh; const float* cwhh;
    const float* Wv; const float* bv;
    float* vout; int* bar;
};

__device__ __forceinline__ void bar_arrive(int* bar)
{
    __syncthreads();   // drains this block's vm/lgkm before t0 releases
    if (threadIdx.x == 0)
        __hip_atomic_fetch_add(bar, 1, __ATOMIC_RELEASE, __HIP_MEMORY_SCOPE_AGENT);
}

__device__ __forceinline__ void bar_wait(int* bar, int target)
{
    if (threadIdx.x == 0) {
        while (__hip_atomic_load(bar, __ATOMIC_RELAXED, __HIP_MEMORY_SCOPE_AGENT) < target)
            __builtin_amdgcn_s_sleep(2);
        (void)__hip_atomic_load(bar, __ATOMIC_ACQUIRE, __HIP_MEMORY_SCOPE_AGENT); // CU L1 inv
    }
    __syncthreads();
}

// acc[g*4+q] += sum_k row[k] * W[k*WC + g*GS + uc4 + q]   (weights: LDS broadcast)
template<int WC, int GS>
__device__ __forceinline__ void gemm16(const float* __restrict__ row,
                                       const float* __restrict__ W,
                                       int uc4, float* acc)
{
    const float4* p = (const float4*)row;
#pragma unroll 4
    for (int k4 = 0; k4 < 16; ++k4) {
        float4 v = p[k4];
        const float* wk = W + (k4 * 4) * WC + uc4;
#pragma unroll
        for (int e = 0; e < 4; ++e) {
            float u = (e == 0) ? v.x : (e == 1) ? v.y : (e == 2) ? v.z : v.w;
            const float* wb = wk + e * WC;
#pragma unroll
            for (int g = 0; g < 4; ++g) {
                float4 w = *(const float4*)(wb + g * GS);
                acc[g * 4 + 0] = fmaf(u, w.x, acc[g * 4 + 0]);
                acc[g * 4 + 1] = fmaf(u, w.y, acc[g * 4 + 1]);
                acc[g * 4 + 2] = fmaf(u, w.z, acc[g * 4 + 2]);
                acc[g * 4 + 3] = fmaf(u, w.w, acc[g * 4 + 3]);
            }
        }
    }
}

__device__ __forceinline__ void cell4(const float* acc, float* c, float* h)
{
#pragma unroll
    for (int q = 0; q < 4; ++q) {
        float iv = sigmf(acc[q]);
        float fv = sigmf(acc[4 + q]);
        float gv = tanhf_(acc[8 + q]);
        float ov = sigmf(acc[12 + q]);
        float c2 = fv * c[q] + iv * gv;
        c[q] = c2;
        h[q] = ov * tanhf_(c2);
    }
}

__global__ __launch_bounds__(1024) void fused_k(KArgs a)
{
    extern __shared__ float sm[];
    const int tid = threadIdx.x;
    const int lane = tid & 63;
    const int wv = tid >> 6;   // 0..15

    if (blockIdx.x < LITB_) {
        // ======== literal block: 128 rows x unit-half (32 units) ========
        const int rowgrp = blockIdx.x >> 1;
        const int half = blockIdx.x & 1;
        const int U0 = half * 32;
        const int Lb = rowgrp * 128;
        float* wih_s = sm;                 // 64x128
        float* whh_s = sm + 8192;
        float* wfl_s = sm + 16384;
        float* buf   = sm + 24576;         // 128 rows x stride 68

        for (int idx = tid; idx < 8192; idx += 1024) {
            int k = idx >> 7, r = idx & 127, g = r >> 5, j = r & 31;
            int src = k * 256 + g * 64 + U0 + j;
            wih_s[idx] = a.lwih[src];
            whh_s[idx] = a.lwhh[src];
            wfl_s[idx] = a.Wfl[src];
        }

        const int rh = wv >> 3, uc = wv & 7, uc4 = uc * 4;
        const int lr = rh * 64 + lane;
        const int R  = Lb + lr;
        const int unit0 = U0 + uc4;
        const int e0 = a.rowptr[R], e1 = a.rowptr[R + 1];
        const float degf = 1.f + (float)(e1 - e0);

        float bias[16];
#pragma unroll
        for (int g = 0; g < 4; ++g)
#pragma unroll
            for (int q = 0; q < 4; ++q)
                bias[g * 4 + q] = a.Bl[g * 64 + unit0 + q] + degf * a.bfl[g * 64 + unit0 + q];

        float lc4[4] = {0.f, 0.f, 0.f, 0.f};
        __syncthreads();

        for (int step = 0; step < STEPS_; ++step) {
            // slot1: preload own out rows (coalesced) -> buf; flip + whh gates from LDS
            for (int s8 = 0; s8 < 8; ++s8) {
                int srow = wv * 8 + s8;
                buf[srow * 68 + lane] = a.out_g[(size_t)(Lb + srow) * 64 + lane];
            }
            __syncthreads();
            float acc[16];
#pragma unroll
            for (int i = 0; i < 16; ++i) acc[i] = bias[i];
            gemm16<128, 32>(buf + (size_t)(lr ^ 1) * 68, wih_s, uc4, acc);   // out[flip] @ wih_top
            if (step) gemm16<128, 32>(buf + (size_t)lr * 68, whh_s, uc4, acc); // lh @ whh
            bar_arrive(a.bar);                          // S2 arrive
            bar_wait(a.bar, (2 * step + 1) * NBLK_);    // S2 wait: chg ready
            // slot2: gather clause h, folded GEMM, cell
            for (int s8 = 0; s8 < 8; ++s8) {
                int srow = wv * 8 + s8;
                int l = Lb + srow;
                int e = a.rowptr[l], eE = a.rowptr[l + 1];
                float v = buf[srow * 68 + lane];
                for (; e + 4 <= eE; e += 4) {
                    float t0 = a.chg[(size_t)a.col[e    ] * 64 + lane];
                    float t1 = a.chg[(size_t)a.col[e + 1] * 64 + lane];
                    float t2 = a.chg[(size_t)a.col[e + 2] * 64 + lane];
                    float t3 = a.chg[(size_t)a.col[e + 3] * 64 + lane];
                    v += t0 + t1 + t2 + t3;
                }
                for (; e < eE; ++e) v += a.chg[(size_t)a.col[e] * 64 + lane];
                buf[srow * 68 + lane] = v;
            }
            __syncthreads();
            gemm16<128, 32>(buf + (size_t)lr * 68, wfl_s, uc4, acc);
            float h2[4];
            cell4(acc, lc4, h2);
            *(float4*)(a.out_g + (size_t)R * 64 + unit0) = make_float4(h2[0], h2[1], h2[2], h2[3]);
            if (step < STEPS_ - 1) {
                bar_arrive(a.bar);                          // S1 arrive
                bar_wait(a.bar, (2 * step + 2) * NBLK_);    // S1 wait
            } else {
                // vote: own 4 units, reduce across the 8 uc-waves, atomic with pair block
                float p = h2[0] * a.Wv[unit0] + h2[1] * a.Wv[unit0 + 1]
                        + h2[2] * a.Wv[unit0 + 2] + h2[3] * a.Wv[unit0 + 3];
                __syncthreads();
                buf[lr * 8 + uc] = p;
                __syncthreads();
                if (uc == 0) {
                    float v = (half == 0) ? a.bv[0] : 0.f;
#pragma unroll
                    for (int w = 0; w < 8; ++w) v += buf[lr * 8 + w];
                    int b = R / NV2_;
                    int pos = R - b * NV2_;
                    int pi = (pos >> 1) + (pos & 1) * 400;   // undo pair-interleave
                    atomicAdd(a.vout + b * NPG_ + pi, v);
                }
            }
        }
    } else {
        // ======== clause block: 128 rows (2 groups of 64), full 64 units ========
        const int Cb = (blockIdx.x - LITB_) * 128;
        float* wfc_s  = sm;             // 64x256
        float* cwhh_s = sm + 16384;     // 64x256
        float* LM     = sm + 32768;     // 64 rows x stride 68
        for (int idx = tid; idx < 16384; idx += 1024) {
            wfc_s[idx]  = a.Wfc[idx];
            cwhh_s[idx] = a.cwhh[idx];
        }
        const int u0 = wv * 4;          // this wave's 4 units
        float bc16[16];
#pragma unroll
        for (int g = 0; g < 4; ++g)
#pragma unroll
            for (int q = 0; q < 4; ++q) bc16[g * 4 + q] = a.Bc[g * 64 + u0 + q];
        float cc_r[2][4] = {};
        float acc2[2][16] = {};
        __syncthreads();

        for (int step = 0; step < STEPS_; ++step) {
            float ch_r[2][4];
            for (int g = 0; g < 2; ++g) {
                // gather lmsg = clause_out + sum of 12 literal outs
                for (int s4 = 0; s4 < 4; ++s4) {
                    int srow = wv * 4 + s4;
                    int c = Cb + g * 64 + srow;
                    float v = step ? a.chg[(size_t)c * 64 + lane]
                                   : a.outc0[(size_t)c * 64 + lane];
                    const int* lp = a.llits + c * KK_;
#pragma unroll
                    for (int k = 0; k < KK_; ++k)
                        v += a.out_g[(size_t)lp[k] * 64 + lane];
                    LM[srow * 68 + lane] = v;
                }
                __syncthreads();
                float acc[16];
#pragma unroll
                for (int i = 0; i < 16; ++i) acc[i] = bc16[i] + acc2[g][i];
                gemm16<256, 64>(LM + (size_t)lane * 68, wfc_s, u0, acc);
                cell4(acc, cc_r[g], ch_r[g]);
                *(float4*)(a.chg + (size_t)(Cb + g * 64 + lane) * 64 + u0) =
                    make_float4(ch_r[g][0], ch_r[g][1], ch_r[g][2], ch_r[g][3]);
                __syncthreads();   // LM reads complete before next group's gather
            }
            bar_arrive(a.bar);     // S2 arrive (chg written); clause skips the S2 wait
            if (step < STEPS_ - 1) {
                // precompute ch(s) @ cwhh for next step while lit does slot2
                for (int g = 0; g < 2; ++g) {
                    *(float4*)(LM + (size_t)lane * 68 + u0) =
                        make_float4(ch_r[g][0], ch_r[g][1], ch_r[g][2], ch_r[g][3]);
                    __syncthreads();
#pragma unroll
                    for (int i = 0; i < 16; ++i) acc2[g][i] = 0.f;
                    gemm16<256, 64>(LM + (size_t)lane * 68, cwhh_s, u0, acc2[g]);
                    __syncthreads();
                }
                bar_arrive(a.bar);                          // S1 arrive
                bar_wait(a.bar, (2 * step + 2) * NBLK_);    // S1 wait
            }
        }
    }
}

// ---------------- host ----------------

extern "C" void kernel_launch(void* const* d_in, const int* in_sizes, int n_in,
                              void* d_out, int out_size, void* d_ws, size_t ws_size,
                              hipStream_t stream)
{
    (void)in_sizes; (void)n_in; (void)out_size; (void)ws_size;
    const float* x    = (const float*)d_in[0];
    const int*   ei   = (const int*)d_in[2];
    const float* liw  = (const float*)d_in[4];
    const float* lib  = (const float*)d_in[5];
    const float* ciw  = (const float*)d_in[6];
    const float* cib  = (const float*)d_in[7];
    const float* lm1  = (const float*)d_in[8];
    const float* lm1b = (const float*)d_in[9];
    const float* lm2  = (const float*)d_in[10];
    const float* lm2b = (const float*)d_in[11];
    const float* lm3  = (const float*)d_in[12];
    const float* lm3b = (const float*)d_in[13];
    const float* cm1  = (const float*)d_in[14];
    const float* cm1b = (const float*)d_in[15];
    const float* cm2  = (const float*)d_in[16];
    const float* cm2b = (const float*)d_in[17];
    const float* cm3  = (const float*)d_in[18];
    const float* cm3b = (const float*)d_in[19];
    const float* lu_wih = (const float*)d_in[20];
    const float* lu_whh = (const float*)d_in[21];
    const float* lu_bih = (const float*)d_in[22];
    const float* lu_bhh = (const float*)d_in[23];
    const float* cu_wih = (const float*)d_in[24];
    const float* cu_whh = (const float*)d_in[25];
    const float* cu_bih = (const float*)d_in[26];
    const float* cu_bhh = (const float*)d_in[27];
    const float* lv1  = (const float*)d_in[28];
    const float* lv1b = (const float*)d_in[29];
    const float* lv2  = (const float*)d_in[30];
    const float* lv2b = (const float*)d_in[31];
    const float* lv3  = (const float*)d_in[32];
    const float* lv3b = (const float*)d_in[33];

    float* F = (float*)d_ws;
    size_t o = 0;
    auto A = [&](size_t n) { float* p = F + o; o += n; return p; };
    float* out_g = A((size_t)NLIT_ * 64);
    float* outc0 = A((size_t)NCLS_ * 64);
    float* chg   = A((size_t)NCLS_ * 64);
    float* Wl    = A(4096);
    float* Wc    = A(4096);
    float* bl    = A(64);
    float* bc    = A(64);
    float* Wv    = A(64);
    float* bv    = A(16);
    float* Wfl   = A(64 * 256);
    float* bfl   = A(256);
    float* Bl    = A(256);
    float* Wfc   = A(64 * 256);
    float* Bc    = A(256);
    int* I = (int*)(F + o);
    int* llits  = I; I += NE_;
    int* rowptr = I; I += 12804;
    int* cursor = I; I += NLIT_;
    int* colA   = I; I += NE_;
    int* cnt    = I; I += NLIT_;
    int* bar    = I; I += 16;

    hipMemsetAsync(cnt, 0, NLIT_ * sizeof(int), stream);
    hipMemsetAsync(bar, 0, sizeof(int), stream);
    hipMemsetAsync(d_out, 0, (size_t)NN_ * sizeof(float), stream);

    collapse_k<<<3, 256, 0, stream>>>(lm1, lm1b, lm2, lm2b, lm3, lm3b,
                                      cm1, cm1b, cm2, cm2b, cm3, cm3b,
                                      lv1, lv1b, lv2, lv2b, lv3, lv3b,
                                      Wl, bl, Wc, bc, Wv, bv);
    fold_k<<<2, 256, 0, stream>>>(Wl, bl, Wc, bc,
                                  lu_wih, lu_bih, lu_bhh,
                                  cu_wih, cu_bih, cu_bhh,
                                  Wfl, bfl, Bl, Wfc, Bc);
    init_k<<<(NN_ * 64 + 255) / 256, 256, 0, stream>>>(x, liw, lib, ciw, cib, out_g, outc0);
    econv_k<<<NE_ / 256, 256, 0, stream>>>(ei, llits, cnt);
    scan_k<<<1, 1024, 0, stream>>>(cnt, rowptr, cursor);
    fill_k<<<NE_ / 256, 256, 0, stream>>>(llits, cursor, colA);

    KArgs ka;
    ka.out_g = out_g; ka.outc0 = outc0; ka.chg = chg;
    ka.llits = llits; ka.rowptr = rowptr; ka.col = colA;
    ka.Wfl = Wfl; ka.bfl = bfl; ka.Bl = Bl; ka.Wfc = Wfc; ka.Bc = Bc;
    ka.lwih = lu_wih; ka.lwhh = lu_whh; ka.cwhh = cu_whh;
    ka.Wv = Wv; ka.bv = bv;
    ka.vout = (float*)d_out;
    ka.bar = bar;

    void* params[] = { &ka };
    hipError_t err = hipLaunchCooperativeKernel((void*)fused_k, dim3(NBLK_), dim3(1024),
                                                params, SMEM_BYTES, stream);
    if (err != hipSuccess) {
        // 255 blocks x 1 per CU are co-resident on 256 CUs regardless
        fused_k<<<NBLK_, 1024, SMEM_BYTES, stream>>>(ka);
    }
}

// Round 4
// 1995.686 us; speedup vs baseline: 2.5306x; 1.2783x over previous
//
#include <hip/hip_runtime.h>
#include <math.h>

// NeuroSAT, MI355X. Round 4: XCD-localized independent barrier groups.
//  - B=16 problems are independent: 8 groups x 32 blocks, 2 problems each,
//    group = blockIdx & 7 (= XCD under round-robin) -> data stays XCD-local,
//    barriers are 32-wide and groups never couple (no global straggler).
//  - Per-step per-phase counters (no monotonic aliasing: fixes the latent
//    run-ahead race of rounds 2/3 AND the 255-way single-line contention).
//  - Block internals identical to round 3 (LDS weights, pair-interleave flip,
//    folded affine MLPs, clause ch@whh precompute overlap) -> same numerics.

#define NV2_   800
#define NC_    440
#define KK_    12
#define NPG_   1240
#define NLIT_  12800
#define NCLS_  7040
#define NE_    84480
#define NN_    19840
#define STEPS_ 23
#define GRP_   8        // independent groups (2 problems each)
#define LITB_G 26       // lit blocks per group: 13 rowgroups x 2 unit-halves
#define CLSB_G 6        // clause blocks per group
#define BLK_G  32
#define NBLK_  256
#define PHSTR_ 16       // ints per barrier counter (cacheline pad)
#define SMEM_BYTES 148480

__device__ __forceinline__ float sigmf(float x) { return 1.0f / (1.0f + __expf(-x)); }
__device__ __forceinline__ float tanhf_(float x) { return 1.0f - 2.0f / (__expf(2.0f * x) + 1.0f); }

// ---------------- setup kernels (unchanged from round 3) ----------------

__global__ __launch_bounds__(256) void collapse_k(
    const float* lm1, const float* lm1b, const float* lm2, const float* lm2b, const float* lm3, const float* lm3b,
    const float* cm1, const float* cm1b, const float* cm2, const float* cm2b, const float* cm3, const float* cm3b,
    const float* lv1, const float* lv1b, const float* lv2, const float* lv2b, const float* lv3, const float* lv3b,
    float* Wl, float* bl, float* Wc, float* bc, float* Wv, float* bv)
{
    __shared__ float T[4096];
    __shared__ float ub[64];
    __shared__ float t3[64];
    int r = blockIdx.x, t = threadIdx.x;
    if (r < 2) {
        const float* w1 = r ? cm1 : lm1; const float* b1 = r ? cm1b : lm1b;
        const float* w2 = r ? cm2 : lm2; const float* b2 = r ? cm2b : lm2b;
        const float* w3 = r ? cm3 : lm3; const float* b3 = r ? cm3b : lm3b;
        float* W = r ? Wc : Wl;  float* bb = r ? bc : bl;
        for (int idx = t; idx < 4096; idx += 256) {
            int i = idx >> 6, j = idx & 63;
            float s = 0.f;
            for (int k = 0; k < 64; ++k) s += w1[i * 64 + k] * w2[k * 64 + j];
            T[idx] = s;
        }
        if (t < 64) {
            float s = 0.f;
            for (int k = 0; k < 64; ++k) s += b1[k] * w2[k * 64 + t];
            ub[t] = s + b2[t];
        }
        __syncthreads();
        for (int idx = t; idx < 4096; idx += 256) {
            int i = idx >> 6, j = idx & 63;
            float s = 0.f;
            for (int k = 0; k < 64; ++k) s += T[i * 64 + k] * w3[k * 64 + j];
            W[idx] = s;
        }
        if (t < 64) {
            float s = 0.f;
            for (int k = 0; k < 64; ++k) s += ub[k] * w3[k * 64 + t];
            bb[t] = s + b3[t];
        }
    } else {
        if (t < 64) {
            float s = 0.f;
            for (int j = 0; j < 64; ++j) s += lv2[t * 64 + j] * lv3[j];
            t3[t] = s;
            float s2 = 0.f;
            for (int k = 0; k < 64; ++k) s2 += lv1b[k] * lv2[k * 64 + t];
            ub[t] = s2 + lv2b[t];
        }
        __syncthreads();
        if (t < 64) {
            float s = 0.f;
            for (int k = 0; k < 64; ++k) s += lv1[t * 64 + k] * t3[k];
            Wv[t] = s;
        }
        if (t == 0) {
            float s = 0.f;
            for (int j = 0; j < 64; ++j) s += ub[j] * lv3[j];
            bv[0] = s + lv3b[0];
        }
    }
}

__global__ __launch_bounds__(256) void fold_k(
    const float* Wl, const float* bl, const float* Wc, const float* bc,
    const float* lwih, const float* lbih, const float* lbhh,
    const float* cwih, const float* cbih, const float* cbhh,
    float* Wfl, float* bfl, float* Bl, float* Wfc, float* Bc)
{
    int j = threadIdx.x;
    if (blockIdx.x == 0) {
        for (int i = 0; i < 64; ++i) {
            float s = 0.f;
            for (int m = 0; m < 64; ++m) s += Wc[i * 64 + m] * lwih[(64 + m) * 256 + j];
            Wfl[i * 256 + j] = s;
        }
        float s = 0.f;
        for (int m = 0; m < 64; ++m) s += bc[m] * lwih[(64 + m) * 256 + j];
        bfl[j] = s;
        Bl[j] = lbih[j] + lbhh[j];
    } else {
        for (int i = 0; i < 64; ++i) {
            float s = 0.f;
            for (int m = 0; m < 64; ++m) s += Wl[i * 64 + m] * cwih[m * 256 + j];
            Wfc[i * 256 + j] = s;
        }
        float s = 0.f;
        for (int m = 0; m < 64; ++m) s += bl[m] * cwih[m * 256 + j];
        Bc[j] = cbih[j] + cbhh[j] + 13.f * s;
    }
}

__global__ __launch_bounds__(256) void init_k(
    const float* x, const float* liw, const float* lib, const float* ciw, const float* cib,
    float* out0, float* outc)
{
    int t = blockIdx.x * 256 + threadIdx.x;
    if (t >= NN_ * 64) return;
    int node = t >> 6, j = t & 63;
    int b = node / NPG_;
    int i = node - b * NPG_;
    float x0 = x[node * 2 + 0], x1 = x[node * 2 + 1];
    if (i < NV2_) {
        int sp = (i < 400) ? 2 * i : 2 * (i - 400) + 1;
        out0[(size_t)(b * NV2_ + sp) * 64 + j] = x0 * liw[j] + x1 * liw[64 + j] + lib[j];
    } else {
        outc[(size_t)(b * NC_ + (i - NV2_)) * 64 + j] = x0 * ciw[j] + x1 * ciw[64 + j] + cib[j];
    }
}

__global__ __launch_bounds__(256) void econv_k(const int* ei, int* llits, int* cnt)
{
    int e = blockIdx.x * 256 + threadIdx.x;
    if (e >= NE_) return;
    int g = ei[e];
    int b = g / NPG_;
    int i = g - b * NPG_;
    int sp = (i < 400) ? 2 * i : 2 * (i - 400) + 1;
    int L = b * NV2_ + sp;
    llits[e] = L;
    atomicAdd(cnt + L, 1);
}

__global__ __launch_bounds__(1024) void scan_k(const int* cnt, int* rowptr, int* cursor)
{
    __shared__ int sums[1024];
    int t = threadIdx.x;
    int i0 = t * 13;
    int i1 = i0 + 13; if (i1 > NLIT_) i1 = NLIT_; if (i0 > NLIT_) i0 = NLIT_;
    int s = 0;
    for (int i = i0; i < i1; ++i) s += cnt[i];
    sums[t] = s;
    __syncthreads();
    for (int off = 1; off < 1024; off <<= 1) {
        int v = (t >= off) ? sums[t - off] : 0;
        __syncthreads();
        sums[t] += v;
        __syncthreads();
    }
    int run = sums[t] - s;
    for (int i = i0; i < i1; ++i) { rowptr[i] = run; cursor[i] = run; run += cnt[i]; }
    if (t == 1023) rowptr[NLIT_] = sums[1023];
}

__global__ __launch_bounds__(256) void fill_k(const int* llits, int* cursor, int* col)
{
    int e = blockIdx.x * 256 + threadIdx.x;
    if (e >= NE_) return;
    int pos = atomicAdd(cursor + llits[e], 1);
    col[pos] = e / KK_;
}

// ---------------- persistent fused kernel ----------------

struct KArgs {
    float* out_g; float* outc0; float* chg;
    const int* llits; const int* rowptr; const int* col;
    const float* Wfl; const float* bfl; const float* Bl;
    const float* Wfc; const float* Bc;
    const float* lwih; const float* lwhh; const float* cwhh;
    const float* Wv; const float* bv;
    float* vout; int* bar;
};

// per-group, per-phase counters: barg[ph*PHSTR_], ph in [0, 46)
__device__ __forceinline__ void bar_arrive(int* barg, int ph)
{
    __syncthreads();   // drains this block's vm/lgkm before t0 releases
    if (threadIdx.x == 0)
        __hip_atomic_fetch_add(barg + ph * PHSTR_, 1, __ATOMIC_RELEASE, __HIP_MEMORY_SCOPE_AGENT);
}

__device__ __forceinline__ void bar_wait(int* barg, int ph)
{
    if (threadIdx.x == 0) {
        while (__hip_atomic_load(barg + ph * PHSTR_, __ATOMIC_RELAXED, __HIP_MEMORY_SCOPE_AGENT) < BLK_G)
            __builtin_amdgcn_s_sleep(1);
        (void)__hip_atomic_load(barg + ph * PHSTR_, __ATOMIC_ACQUIRE, __HIP_MEMORY_SCOPE_AGENT);
    }
    __syncthreads();
}

// acc[g*4+q] += sum_k row[k] * W[k*WC + g*GS + uc4 + q]   (weights: LDS broadcast)
template<int WC, int GS>
__device__ __forceinline__ void gemm16(const float* __restrict__ row,
                                       const float* __restrict__ W,
                                       int uc4, float* acc)
{
    const float4* p = (const float4*)row;
#pragma unroll 4
    for (int k4 = 0; k4 < 16; ++k4) {
        float4 v = p[k4];
        const float* wk = W + (k4 * 4) * WC + uc4;
#pragma unroll
        for (int e = 0; e < 4; ++e) {
            float u = (e == 0) ? v.x : (e == 1) ? v.y : (e == 2) ? v.z : v.w;
            const float* wb = wk + e * WC;
#pragma unroll
            for (int g = 0; g < 4; ++g) {
                float4 w = *(const float4*)(wb + g * GS);
                acc[g * 4 + 0] = fmaf(u, w.x, acc[g * 4 + 0]);
                acc[g * 4 + 1] = fmaf(u, w.y, acc[g * 4 + 1]);
                acc[g * 4 + 2] = fmaf(u, w.z, acc[g * 4 + 2]);
                acc[g * 4 + 3] = fmaf(u, w.w, acc[g * 4 + 3]);
            }
        }
    }
}

__device__ __forceinline__ void cell4(const float* acc, float* c, float* h)
{
#pragma unroll
    for (int q = 0; q < 4; ++q) {
        float iv = sigmf(acc[q]);
        float fv = sigmf(acc[4 + q]);
        float gv = tanhf_(acc[8 + q]);
        float ov = sigmf(acc[12 + q]);
        float c2 = fv * c[q] + iv * gv;
        c[q] = c2;
        h[q] = ov * tanhf_(c2);
    }
}

__global__ __launch_bounds__(1024) void fused_k(KArgs a)
{
    extern __shared__ float sm[];
    const int tid = threadIdx.x;
    const int lane = tid & 63;
    const int wv = tid >> 6;                 // 0..15
    const int grp = blockIdx.x & 7;          // group == XCD under round-robin
    const int idx = blockIdx.x >> 3;         // role within group: 0..31
    int* barg = a.bar + grp * 48 * PHSTR_;

    if (idx < LITB_G) {
        // ======== literal block: <=128 rows x unit-half (32 units) ========
        const int rowgrp = idx >> 1;
        const int half = idx & 1;
        const int U0 = half * 32;
        const int Lb = grp * 1600 + rowgrp * 128;
        const int nrows = (rowgrp < 12) ? 128 : 64;   // group has 1600 lit rows
        float* wih_s = sm;                 // 64x128 (unit-half slice)
        float* whh_s = sm + 8192;
        float* wfl_s = sm + 16384;
        float* buf   = sm + 24576;         // 128 rows x stride 68

        for (int i2 = tid; i2 < 8192; i2 += 1024) {
            int k = i2 >> 7, r = i2 & 127, gg = r >> 5, j = r & 31;
            int src = k * 256 + gg * 64 + U0 + j;
            wih_s[i2] = a.lwih[src];
            whh_s[i2] = a.lwhh[src];
            wfl_s[i2] = a.Wfl[src];
        }

        const int rh = wv >> 3, uc = wv & 7, uc4 = uc * 4;
        const int lr = rh * 64 + lane;
        const bool vrow = (lr < nrows);
        const int R = Lb + (vrow ? lr : 0);
        const int unit0 = U0 + uc4;
        const float degf = 1.f + (float)(a.rowptr[R + 1] - a.rowptr[R]);

        float bias[16];
#pragma unroll
        for (int g = 0; g < 4; ++g)
#pragma unroll
            for (int q = 0; q < 4; ++q)
                bias[g * 4 + q] = a.Bl[g * 64 + unit0 + q] + degf * a.bfl[g * 64 + unit0 + q];

        float lc4[4] = {0.f, 0.f, 0.f, 0.f};
        __syncthreads();

        for (int step = 0; step < STEPS_; ++step) {
            // slot1 (overlaps clause main): preload own rows; flip + whh gates
            for (int s8 = 0; s8 < 8; ++s8) {
                int srow = wv * 8 + s8;
                if (srow < nrows)
                    buf[srow * 68 + lane] = a.out_g[(size_t)(Lb + srow) * 64 + lane];
            }
            __syncthreads();
            float acc[16];
#pragma unroll
            for (int i = 0; i < 16; ++i) acc[i] = bias[i];
            gemm16<128, 32>(buf + (size_t)(lr ^ 1) * 68, wih_s, uc4, acc);     // out[flip] @ wih_top
            if (step) gemm16<128, 32>(buf + (size_t)lr * 68, whh_s, uc4, acc); // lh @ whh
            bar_arrive(barg, 2 * step);        // S2 arrive (also certifies out_g reads done)
            bar_wait(barg, 2 * step);          // S2 wait: chg(step) ready
            // slot2: gather clause h, folded GEMM, cell
            for (int s8 = 0; s8 < 8; ++s8) {
                int srow = wv * 8 + s8;
                if (srow >= nrows) continue;
                int l = Lb + srow;
                int e = a.rowptr[l], eE = a.rowptr[l + 1];
                float v = buf[srow * 68 + lane];
                for (; e + 4 <= eE; e += 4) {
                    float t0 = a.chg[(size_t)a.col[e    ] * 64 + lane];
                    float t1 = a.chg[(size_t)a.col[e + 1] * 64 + lane];
                    float t2 = a.chg[(size_t)a.col[e + 2] * 64 + lane];
                    float t3 = a.chg[(size_t)a.col[e + 3] * 64 + lane];
                    v += t0 + t1 + t2 + t3;
                }
                for (; e < eE; ++e) v += a.chg[(size_t)a.col[e] * 64 + lane];
                buf[srow * 68 + lane] = v;
            }
            __syncthreads();
            gemm16<128, 32>(buf + (size_t)lr * 68, wfl_s, uc4, acc);
            float h2[4];
            cell4(acc, lc4, h2);
            if (vrow)
                *(float4*)(a.out_g + (size_t)R * 64 + unit0) = make_float4(h2[0], h2[1], h2[2], h2[3]);
            if (step < STEPS_ - 1) {
                bar_arrive(barg, 2 * step + 1);    // S1 arrive (out_g written, chg reads done)
                bar_wait(barg, 2 * step + 1);
            } else {
                // vote epilogue
                float p = h2[0] * a.Wv[unit0] + h2[1] * a.Wv[unit0 + 1]
                        + h2[2] * a.Wv[unit0 + 2] + h2[3] * a.Wv[unit0 + 3];
                __syncthreads();
                if (vrow) buf[lr * 8 + uc] = p;
                __syncthreads();
                if (uc == 0 && vrow) {
                    float v = (half == 0) ? a.bv[0] : 0.f;
#pragma unroll
                    for (int w = 0; w < 8; ++w) v += buf[lr * 8 + w];
                    int b = R / NV2_;
                    int pos = R - b * NV2_;
                    int pi = (pos >> 1) + (pos & 1) * 400;   // undo pair-interleave
                    atomicAdd(a.vout + b * NPG_ + pi, v);
                }
            }
        }
    } else {
        // ======== clause block: ~147 rows (3 subgroups of <=64), full 64 units ========
        const int ci = idx - LITB_G;                         // 0..5
        const int rows = (ci < 4) ? 147 : 146;               // 880 rows per group
        const int c0 = grp * 880 + ci * 147 - ((ci > 4) ? (ci - 4) : 0);
        float* wfc_s  = sm;             // 64x256
        float* cwhh_s = sm + 16384;     // 64x256
        float* LM     = sm + 32768;     // 64 rows x stride 68
        for (int i2 = tid; i2 < 16384; i2 += 1024) {
            wfc_s[i2]  = a.Wfc[i2];
            cwhh_s[i2] = a.cwhh[i2];
        }
        const int u0 = wv * 4;          // this wave's 4 units
        float bc16[16];
#pragma unroll
        for (int g = 0; g < 4; ++g)
#pragma unroll
            for (int q = 0; q < 4; ++q) bc16[g * 4 + q] = a.Bc[g * 64 + u0 + q];
        float cc_r[3][4] = {};
        float acc2[3][16] = {};
        __syncthreads();

        for (int step = 0; step < STEPS_; ++step) {
            float ch_r[3][4];
#pragma unroll 1
            for (int sg = 0; sg < 3; ++sg) {
                const int r0 = sg * 64;
                const int cnt = (rows - r0 < 64) ? (rows - r0) : 64;
                // gather lmsg = clause_out + sum of 12 literal outs
                for (int s4 = 0; s4 < 4; ++s4) {
                    int srow = wv * 4 + s4;
                    if (srow < cnt) {
                        int c = c0 + r0 + srow;
                        float v = step ? a.chg[(size_t)c * 64 + lane]
                                       : a.outc0[(size_t)c * 64 + lane];
                        const int* lp = a.llits + c * KK_;
#pragma unroll
                        for (int k = 0; k < KK_; ++k)
                            v += a.out_g[(size_t)lp[k] * 64 + lane];
                        LM[srow * 68 + lane] = v;
                    }
                }
                __syncthreads();
                float acc[16];
#pragma unroll
                for (int i = 0; i < 16; ++i) acc[i] = bc16[i] + acc2[sg][i];
                gemm16<256, 64>(LM + (size_t)lane * 68, wfc_s, u0, acc);
                cell4(acc, cc_r[sg], ch_r[sg]);
                if (lane < cnt)
                    *(float4*)(a.chg + (size_t)(c0 + r0 + lane) * 64 + u0) =
                        make_float4(ch_r[sg][0], ch_r[sg][1], ch_r[sg][2], ch_r[sg][3]);
                __syncthreads();   // LM reads complete before next subgroup's gather
            }
            bar_arrive(barg, 2 * step);    // S2 arrive (chg written); clause skips S2 wait
            if (step < STEPS_ - 1) {
                // precompute ch(step) @ cwhh for next step while lit does slot2
#pragma unroll 1
                for (int sg = 0; sg < 3; ++sg) {
                    *(float4*)(LM + (size_t)lane * 68 + u0) =
                        make_float4(ch_r[sg][0], ch_r[sg][1], ch_r[sg][2], ch_r[sg][3]);
                    __syncthreads();
#pragma unroll
                    for (int i = 0; i < 16; ++i) acc2[sg][i] = 0.f;
                    gemm16<256, 64>(LM + (size_t)lane * 68, cwhh_s, u0, acc2[sg]);
                    __syncthreads();
                }
                bar_arrive(barg, 2 * step + 1);    // S1 arrive
                bar_wait(barg, 2 * step + 1);      // S1 wait: out_g(step+1) ready
            }
        }
    }
}

// ---------------- host ----------------

extern "C" void kernel_launch(void* const* d_in, const int* in_sizes, int n_in,
                              void* d_out, int out_size, void* d_ws, size_t ws_size,
                              hipStream_t stream)
{
    (void)in_sizes; (void)n_in; (void)out_size; (void)ws_size;
    const float* x    = (const float*)d_in[0];
    const int*   ei   = (const int*)d_in[2];
    const float* liw  = (const float*)d_in[4];
    const float* lib  = (const float*)d_in[5];
    const float* ciw  = (const float*)d_in[6];
    const float* cib  = (const float*)d_in[7];
    const float* lm1  = (const float*)d_in[8];
    const float* lm1b = (const float*)d_in[9];
    const float* lm2  = (const float*)d_in[10];
    const float* lm2b = (const float*)d_in[11];
    const float* lm3  = (const float*)d_in[12];
    const float* lm3b = (const float*)d_in[13];
    const float* cm1  = (const float*)d_in[14];
    const float* cm1b = (const float*)d_in[15];
    const float* cm2  = (const float*)d_in[16];
    const float* cm2b = (const float*)d_in[17];
    const float* cm3  = (const float*)d_in[18];
    const float* cm3b = (const float*)d_in[19];
    const float* lu_wih = (const float*)d_in[20];
    const float* lu_whh = (const float*)d_in[21];
    const float* lu_bih = (const float*)d_in[22];
    const float* lu_bhh = (const float*)d_in[23];
    const float* cu_wih = (const float*)d_in[24];
    const float* cu_whh = (const float*)d_in[25];
    const float* cu_bih = (const float*)d_in[26];
    const float* cu_bhh = (const float*)d_in[27];
    const float* lv1  = (const float*)d_in[28];
    const float* lv1b = (const float*)d_in[29];
    const float* lv2  = (const float*)d_in[30];
    const float* lv2b = (const float*)d_in[31];
    const float* lv3  = (const float*)d_in[32];
    const float* lv3b = (const float*)d_in[33];

    float* F = (float*)d_ws;
    size_t o = 0;
    auto A = [&](size_t n) { float* p = F + o; o += n; return p; };
    float* out_g = A((size_t)NLIT_ * 64);
    float* outc0 = A((size_t)NCLS_ * 64);
    float* chg   = A((size_t)NCLS_ * 64);
    float* Wl    = A(4096);
    float* Wc    = A(4096);
    float* bl    = A(64);
    float* bc    = A(64);
    float* Wv    = A(64);
    float* bv    = A(16);
    float* Wfl   = A(64 * 256);
    float* bfl   = A(256);
    float* Bl    = A(256);
    float* Wfc   = A(64 * 256);
    float* Bc    = A(256);
    int* I = (int*)(F + o);
    int* llits  = I; I += NE_;
    int* rowptr = I; I += 12804;
    int* cursor = I; I += NLIT_;
    int* colA   = I; I += NE_;
    int* cnt    = I; I += NLIT_;
    int* bar    = I; I += GRP_ * 48 * PHSTR_;

    hipMemsetAsync(cnt, 0, NLIT_ * sizeof(int), stream);
    hipMemsetAsync(bar, 0, GRP_ * 48 * PHSTR_ * sizeof(int), stream);
    hipMemsetAsync(d_out, 0, (size_t)NN_ * sizeof(float), stream);

    collapse_k<<<3, 256, 0, stream>>>(lm1, lm1b, lm2, lm2b, lm3, lm3b,
                                      cm1, cm1b, cm2, cm2b, cm3, cm3b,
                                      lv1, lv1b, lv2, lv2b, lv3, lv3b,
                                      Wl, bl, Wc, bc, Wv, bv);
    fold_k<<<2, 256, 0, stream>>>(Wl, bl, Wc, bc,
                                  lu_wih, lu_bih, lu_bhh,
                                  cu_wih, cu_bih, cu_bhh,
                                  Wfl, bfl, Bl, Wfc, Bc);
    init_k<<<(NN_ * 64 + 255) / 256, 256, 0, stream>>>(x, liw, lib, ciw, cib, out_g, outc0);
    econv_k<<<NE_ / 256, 256, 0, stream>>>(ei, llits, cnt);
    scan_k<<<1, 1024, 0, stream>>>(cnt, rowptr, cursor);
    fill_k<<<NE_ / 256, 256, 0, stream>>>(llits, cursor, colA);

    KArgs ka;
    ka.out_g = out_g; ka.outc0 = outc0; ka.chg = chg;
    ka.llits = llits; ka.rowptr = rowptr; ka.col = colA;
    ka.Wfl = Wfl; ka.bfl = bfl; ka.Bl = Bl; ka.Wfc = Wfc; ka.Bc = Bc;
    ka.lwih = lu_wih; ka.lwhh = lu_whh; ka.cwhh = cu_whh;
    ka.Wv = Wv; ka.bv = bv;
    ka.vout = (float*)d_out;
    ka.bar = bar;

    void* params[] = { &ka };
    hipError_t err = hipLaunchCooperativeKernel((void*)fused_k, dim3(NBLK_), dim3(1024),
                                                params, SMEM_BYTES, stream);
    if (err != hipSuccess) {
        // 256 blocks x 1 per CU are co-resident on 256 CUs regardless
        fused_k<<<NBLK_, 1024, SMEM_BYTES, stream>>>(ka);
    }
}

// Round 5
// 1929.957 us; speedup vs baseline: 2.6168x; 1.0341x over previous
//
#include <hip/hip_runtime.h>
#include <math.h>

// NeuroSAT, MI355X. Round 5: flush-free coherence.
//  - Round-4 stall was agent acquire/release cache maintenance: RELEASE wrote
//    back dirty L2 (448MB total, 4x-amplified by gather-thrash evicting
//    partially written lines), ACQUIRE invalidated the XCD L2 every half-step
//    (evicting col/llits/rowptr -> refetched each step).
//  - Now ALL cross-block data (out_g, chg) moves via device-scope RELAXED
//    atomic loads/stores (global_load/store sc1: bypass L1+L2, LLC-coherent).
//    L2 never holds comm data -> release writeback finds ~nothing; the wait
//    side needs NO acquire/invalidate (sc1 loads can't see stale caches) ->
//    L2 stays hot for the read-only index arrays.
//  - Barrier/grouping/arithmetic identical to round 4 (8 XCD-local groups of
//    32 blocks, per-phase counters). Bit-identical numerics: absmax 0.01367.

#define NV2_   800
#define NC_    440
#define KK_    12
#define NPG_   1240
#define NLIT_  12800
#define NCLS_  7040
#define NE_    84480
#define NN_    19840
#define STEPS_ 23
#define GRP_   8
#define LITB_G 26
#define CLSB_G 6
#define BLK_G  32
#define NBLK_  256
#define PHSTR_ 16
#define SMEM_BYTES 148480

__device__ __forceinline__ float sigmf(float x) { return 1.0f / (1.0f + __expf(-x)); }
__device__ __forceinline__ float tanhf_(float x) { return 1.0f - 2.0f / (__expf(2.0f * x) + 1.0f); }

// device-coherent (sc1) access helpers: bypass L1/L2, LLC is the common point
__device__ __forceinline__ float ldg_sc(const float* p)
{
    return __hip_atomic_load(p, __ATOMIC_RELAXED, __HIP_MEMORY_SCOPE_AGENT);
}
__device__ __forceinline__ void stg_sc2(float* p, float a, float b)
{
    union { float f[2]; unsigned long long u; } x;
    x.f[0] = a; x.f[1] = b;
    __hip_atomic_store((unsigned long long*)p, x.u, __ATOMIC_RELAXED, __HIP_MEMORY_SCOPE_AGENT);
}

// ---------------- setup kernels (unchanged) ----------------

__global__ __launch_bounds__(256) void collapse_k(
    const float* lm1, const float* lm1b, const float* lm2, const float* lm2b, const float* lm3, const float* lm3b,
    const float* cm1, const float* cm1b, const float* cm2, const float* cm2b, const float* cm3, const float* cm3b,
    const float* lv1, const float* lv1b, const float* lv2, const float* lv2b, const float* lv3, const float* lv3b,
    float* Wl, float* bl, float* Wc, float* bc, float* Wv, float* bv)
{
    __shared__ float T[4096];
    __shared__ float ub[64];
    __shared__ float t3[64];
    int r = blockIdx.x, t = threadIdx.x;
    if (r < 2) {
        const float* w1 = r ? cm1 : lm1; const float* b1 = r ? cm1b : lm1b;
        const float* w2 = r ? cm2 : lm2; const float* b2 = r ? cm2b : lm2b;
        const float* w3 = r ? cm3 : lm3; const float* b3 = r ? cm3b : lm3b;
        float* W = r ? Wc : Wl;  float* bb = r ? bc : bl;
        for (int idx = t; idx < 4096; idx += 256) {
            int i = idx >> 6, j = idx & 63;
            float s = 0.f;
            for (int k = 0; k < 64; ++k) s += w1[i * 64 + k] * w2[k * 64 + j];
            T[idx] = s;
        }
        if (t < 64) {
            float s = 0.f;
            for (int k = 0; k < 64; ++k) s += b1[k] * w2[k * 64 + t];
            ub[t] = s + b2[t];
        }
        __syncthreads();
        for (int idx = t; idx < 4096; idx += 256) {
            int i = idx >> 6, j = idx & 63;
            float s = 0.f;
            for (int k = 0; k < 64; ++k) s += T[i * 64 + k] * w3[k * 64 + j];
            W[idx] = s;
        }
        if (t < 64) {
            float s = 0.f;
            for (int k = 0; k < 64; ++k) s += ub[k] * w3[k * 64 + t];
            bb[t] = s + b3[t];
        }
    } else {
        if (t < 64) {
            float s = 0.f;
            for (int j = 0; j < 64; ++j) s += lv2[t * 64 + j] * lv3[j];
            t3[t] = s;
            float s2 = 0.f;
            for (int k = 0; k < 64; ++k) s2 += lv1b[k] * lv2[k * 64 + t];
            ub[t] = s2 + lv2b[t];
        }
        __syncthreads();
        if (t < 64) {
            float s = 0.f;
            for (int k = 0; k < 64; ++k) s += lv1[t * 64 + k] * t3[k];
            Wv[t] = s;
        }
        if (t == 0) {
            float s = 0.f;
            for (int j = 0; j < 64; ++j) s += ub[j] * lv3[j];
            bv[0] = s + lv3b[0];
        }
    }
}

__global__ __launch_bounds__(256) void fold_k(
    const float* Wl, const float* bl, const float* Wc, const float* bc,
    const float* lwih, const float* lbih, const float* lbhh,
    const float* cwih, const float* cbih, const float* cbhh,
    float* Wfl, float* bfl, float* Bl, float* Wfc, float* Bc)
{
    int j = threadIdx.x;
    if (blockIdx.x == 0) {
        for (int i = 0; i < 64; ++i) {
            float s = 0.f;
            for (int m = 0; m < 64; ++m) s += Wc[i * 64 + m] * lwih[(64 + m) * 256 + j];
            Wfl[i * 256 + j] = s;
        }
        float s = 0.f;
        for (int m = 0; m < 64; ++m) s += bc[m] * lwih[(64 + m) * 256 + j];
        bfl[j] = s;
        Bl[j] = lbih[j] + lbhh[j];
    } else {
        for (int i = 0; i < 64; ++i) {
            float s = 0.f;
            for (int m = 0; m < 64; ++m) s += Wl[i * 64 + m] * cwih[m * 256 + j];
            Wfc[i * 256 + j] = s;
        }
        float s = 0.f;
        for (int m = 0; m < 64; ++m) s += bl[m] * cwih[m * 256 + j];
        Bc[j] = cbih[j] + cbhh[j] + 13.f * s;
    }
}

__global__ __launch_bounds__(256) void init_k(
    const float* x, const float* liw, const float* lib, const float* ciw, const float* cib,
    float* out0, float* outc)
{
    int t = blockIdx.x * 256 + threadIdx.x;
    if (t >= NN_ * 64) return;
    int node = t >> 6, j = t & 63;
    int b = node / NPG_;
    int i = node - b * NPG_;
    float x0 = x[node * 2 + 0], x1 = x[node * 2 + 1];
    if (i < NV2_) {
        int sp = (i < 400) ? 2 * i : 2 * (i - 400) + 1;
        out0[(size_t)(b * NV2_ + sp) * 64 + j] = x0 * liw[j] + x1 * liw[64 + j] + lib[j];
    } else {
        outc[(size_t)(b * NC_ + (i - NV2_)) * 64 + j] = x0 * ciw[j] + x1 * ciw[64 + j] + cib[j];
    }
}

__global__ __launch_bounds__(256) void econv_k(const int* ei, int* llits, int* cnt)
{
    int e = blockIdx.x * 256 + threadIdx.x;
    if (e >= NE_) return;
    int g = ei[e];
    int b = g / NPG_;
    int i = g - b * NPG_;
    int sp = (i < 400) ? 2 * i : 2 * (i - 400) + 1;
    int L = b * NV2_ + sp;
    llits[e] = L;
    atomicAdd(cnt + L, 1);
}

__global__ __launch_bounds__(1024) void scan_k(const int* cnt, int* rowptr, int* cursor)
{
    __shared__ int sums[1024];
    int t = threadIdx.x;
    int i0 = t * 13;
    int i1 = i0 + 13; if (i1 > NLIT_) i1 = NLIT_; if (i0 > NLIT_) i0 = NLIT_;
    int s = 0;
    for (int i = i0; i < i1; ++i) s += cnt[i];
    sums[t] = s;
    __syncthreads();
    for (int off = 1; off < 1024; off <<= 1) {
        int v = (t >= off) ? sums[t - off] : 0;
        __syncthreads();
        sums[t] += v;
        __syncthreads();
    }
    int run = sums[t] - s;
    for (int i = i0; i < i1; ++i) { rowptr[i] = run; cursor[i] = run; run += cnt[i]; }
    if (t == 1023) rowptr[NLIT_] = sums[1023];
}

__global__ __launch_bounds__(256) void fill_k(const int* llits, int* cursor, int* col)
{
    int e = blockIdx.x * 256 + threadIdx.x;
    if (e >= NE_) return;
    int pos = atomicAdd(cursor + llits[e], 1);
    col[pos] = e / KK_;
}

// ---------------- persistent fused kernel ----------------

struct KArgs {
    float* out_g; float* outc0; float* chg;
    const int* llits; const int* rowptr; const int* col;
    const float* Wfl; const float* bfl; const float* Bl;
    const float* Wfc; const float* Bc;
    const float* lwih; const float* lwhh; const float* cwhh;
    const float* Wv; const float* bv;
    float* vout; int* bar;
};

// arrive: RELEASE (wb is ~free: comm data never dirties L2). wait: RELAXED
// spin + compiler barrier (no invalidate -> L2 stays hot for index arrays;
// sc1 data loads cannot observe stale caches by construction).
__device__ __forceinline__ void bar_arrive(int* barg, int ph)
{
    __syncthreads();   // drains this block's vm/lgkm before t0 releases
    if (threadIdx.x == 0)
        __hip_atomic_fetch_add(barg + ph * PHSTR_, 1, __ATOMIC_RELEASE, __HIP_MEMORY_SCOPE_AGENT);
}

__device__ __forceinline__ void bar_wait(int* barg, int ph)
{
    if (threadIdx.x == 0) {
        while (__hip_atomic_load(barg + ph * PHSTR_, __ATOMIC_RELAXED, __HIP_MEMORY_SCOPE_AGENT) < BLK_G)
            __builtin_amdgcn_s_sleep(1);
    }
    asm volatile("" ::: "memory");
    __syncthreads();
}

// acc[g*4+q] += sum_k row[k] * W[k*WC + g*GS + uc4 + q]   (weights: LDS broadcast)
template<int WC, int GS>
__device__ __forceinline__ void gemm16(const float* __restrict__ row,
                                       const float* __restrict__ W,
                                       int uc4, float* acc)
{
    const float4* p = (const float4*)row;
#pragma unroll 4
    for (int k4 = 0; k4 < 16; ++k4) {
        float4 v = p[k4];
        const float* wk = W + (k4 * 4) * WC + uc4;
#pragma unroll
        for (int e = 0; e < 4; ++e) {
            float u = (e == 0) ? v.x : (e == 1) ? v.y : (e == 2) ? v.z : v.w;
            const float* wb = wk + e * WC;
#pragma unroll
            for (int g = 0; g < 4; ++g) {
                float4 w = *(const float4*)(wb + g * GS);
                acc[g * 4 + 0] = fmaf(u, w.x, acc[g * 4 + 0]);
                acc[g * 4 + 1] = fmaf(u, w.y, acc[g * 4 + 1]);
                acc[g * 4 + 2] = fmaf(u, w.z, acc[g * 4 + 2]);
                acc[g * 4 + 3] = fmaf(u, w.w, acc[g * 4 + 3]);
            }
        }
    }
}

__device__ __forceinline__ void cell4(const float* acc, float* c, float* h)
{
#pragma unroll
    for (int q = 0; q < 4; ++q) {
        float iv = sigmf(acc[q]);
        float fv = sigmf(acc[4 + q]);
        float gv = tanhf_(acc[8 + q]);
        float ov = sigmf(acc[12 + q]);
        float c2 = fv * c[q] + iv * gv;
        c[q] = c2;
        h[q] = ov * tanhf_(c2);
    }
}

__global__ __launch_bounds__(1024) void fused_k(KArgs a)
{
    extern __shared__ float sm[];
    const int tid = threadIdx.x;
    const int lane = tid & 63;
    const int wv = tid >> 6;                 // 0..15
    const int grp = blockIdx.x & 7;          // group == XCD under round-robin
    const int idx = blockIdx.x >> 3;         // role within group: 0..31
    int* barg = a.bar + grp * 48 * PHSTR_;

    if (idx < LITB_G) {
        // ======== literal block: <=128 rows x unit-half (32 units) ========
        const int rowgrp = idx >> 1;
        const int half = idx & 1;
        const int U0 = half * 32;
        const int Lb = grp * 1600 + rowgrp * 128;
        const int nrows = (rowgrp < 12) ? 128 : 64;
        float* wih_s = sm;                 // 64x128 (unit-half slice)
        float* whh_s = sm + 8192;
        float* wfl_s = sm + 16384;
        float* buf   = sm + 24576;         // 128 rows x stride 68

        for (int i2 = tid; i2 < 8192; i2 += 1024) {
            int k = i2 >> 7, r = i2 & 127, gg = r >> 5, j = r & 31;
            int src = k * 256 + gg * 64 + U0 + j;
            wih_s[i2] = a.lwih[src];
            whh_s[i2] = a.lwhh[src];
            wfl_s[i2] = a.Wfl[src];
        }

        const int rh = wv >> 3, uc = wv & 7, uc4 = uc * 4;
        const int lr = rh * 64 + lane;
        const bool vrow = (lr < nrows);
        const int R = Lb + (vrow ? lr : 0);
        const int unit0 = U0 + uc4;
        const float degf = 1.f + (float)(a.rowptr[R + 1] - a.rowptr[R]);

        float bias[16];
#pragma unroll
        for (int g = 0; g < 4; ++g)
#pragma unroll
            for (int q = 0; q < 4; ++q)
                bias[g * 4 + q] = a.Bl[g * 64 + unit0 + q] + degf * a.bfl[g * 64 + unit0 + q];

        float lc4[4] = {0.f, 0.f, 0.f, 0.f};
        __syncthreads();

        for (int step = 0; step < STEPS_; ++step) {
            // slot1 (overlaps clause main): preload own rows; flip + whh gates
            for (int s8 = 0; s8 < 8; ++s8) {
                int srow = wv * 8 + s8;
                if (srow < nrows)
                    buf[srow * 68 + lane] = ldg_sc(a.out_g + (size_t)(Lb + srow) * 64 + lane);
            }
            __syncthreads();
            float acc[16];
#pragma unroll
            for (int i = 0; i < 16; ++i) acc[i] = bias[i];
            gemm16<128, 32>(buf + (size_t)(lr ^ 1) * 68, wih_s, uc4, acc);     // out[flip] @ wih_top
            if (step) gemm16<128, 32>(buf + (size_t)lr * 68, whh_s, uc4, acc); // lh @ whh
            bar_arrive(barg, 2 * step);        // S2 arrive (out_g reads done)
            bar_wait(barg, 2 * step);          // S2 wait: chg(step) ready
            // slot2: gather clause h, folded GEMM, cell
            for (int s8 = 0; s8 < 8; ++s8) {
                int srow = wv * 8 + s8;
                if (srow >= nrows) continue;
                int l = Lb + srow;
                int e = a.rowptr[l], eE = a.rowptr[l + 1];
                float v = buf[srow * 68 + lane];
                for (; e + 4 <= eE; e += 4) {
                    float t0 = ldg_sc(a.chg + (size_t)a.col[e    ] * 64 + lane);
                    float t1 = ldg_sc(a.chg + (size_t)a.col[e + 1] * 64 + lane);
                    float t2 = ldg_sc(a.chg + (size_t)a.col[e + 2] * 64 + lane);
                    float t3 = ldg_sc(a.chg + (size_t)a.col[e + 3] * 64 + lane);
                    v += t0 + t1 + t2 + t3;
                }
                for (; e < eE; ++e) v += ldg_sc(a.chg + (size_t)a.col[e] * 64 + lane);
                buf[srow * 68 + lane] = v;
            }
            __syncthreads();
            gemm16<128, 32>(buf + (size_t)lr * 68, wfl_s, uc4, acc);
            float h2[4];
            cell4(acc, lc4, h2);
            if (vrow) {
                float* dp = a.out_g + (size_t)R * 64 + unit0;
                stg_sc2(dp,     h2[0], h2[1]);
                stg_sc2(dp + 2, h2[2], h2[3]);
            }
            if (step < STEPS_ - 1) {
                bar_arrive(barg, 2 * step + 1);    // S1 arrive (out_g written, chg reads done)
                bar_wait(barg, 2 * step + 1);
            } else {
                // vote epilogue
                float p = h2[0] * a.Wv[unit0] + h2[1] * a.Wv[unit0 + 1]
                        + h2[2] * a.Wv[unit0 + 2] + h2[3] * a.Wv[unit0 + 3];
                __syncthreads();
                if (vrow) buf[lr * 8 + uc] = p;
                __syncthreads();
                if (uc == 0 && vrow) {
                    float v = (half == 0) ? a.bv[0] : 0.f;
#pragma unroll
                    for (int w = 0; w < 8; ++w) v += buf[lr * 8 + w];
                    int b = R / NV2_;
                    int pos = R - b * NV2_;
                    int pi = (pos >> 1) + (pos & 1) * 400;   // undo pair-interleave
                    atomicAdd(a.vout + b * NPG_ + pi, v);
                }
            }
        }
    } else {
        // ======== clause block: ~147 rows (3 subgroups of <=64), full 64 units ========
        const int ci = idx - LITB_G;                         // 0..5
        const int rows = (ci < 4) ? 147 : 146;               // 880 rows per group
        const int c0 = grp * 880 + ci * 147 - ((ci > 4) ? (ci - 4) : 0);
        float* wfc_s  = sm;             // 64x256
        float* cwhh_s = sm + 16384;     // 64x256
        float* LM     = sm + 32768;     // 64 rows x stride 68
        for (int i2 = tid; i2 < 16384; i2 += 1024) {
            wfc_s[i2]  = a.Wfc[i2];
            cwhh_s[i2] = a.cwhh[i2];
        }
        const int u0 = wv * 4;          // this wave's 4 units
        float bc16[16];
#pragma unroll
        for (int g = 0; g < 4; ++g)
#pragma unroll
            for (int q = 0; q < 4; ++q) bc16[g * 4 + q] = a.Bc[g * 64 + u0 + q];
        float cc_r[3][4] = {};
        float acc2[3][16] = {};
        __syncthreads();

        for (int step = 0; step < STEPS_; ++step) {
            float ch_r[3][4];
#pragma unroll 1
            for (int sg = 0; sg < 3; ++sg) {
                const int r0 = sg * 64;
                const int cnt = (rows - r0 < 64) ? (rows - r0) : 64;
                // gather lmsg = clause_out + sum of 12 literal outs
                for (int s4 = 0; s4 < 4; ++s4) {
                    int srow = wv * 4 + s4;
                    if (srow < cnt) {
                        int c = c0 + r0 + srow;
                        float v = step ? ldg_sc(a.chg + (size_t)c * 64 + lane)
                                       : a.outc0[(size_t)c * 64 + lane];
                        const int* lp = a.llits + c * KK_;
#pragma unroll
                        for (int k = 0; k < KK_; ++k)
                            v += ldg_sc(a.out_g + (size_t)lp[k] * 64 + lane);
                        LM[srow * 68 + lane] = v;
                    }
                }
                __syncthreads();
                float acc[16];
#pragma unroll
                for (int i = 0; i < 16; ++i) acc[i] = bc16[i] + acc2[sg][i];
                gemm16<256, 64>(LM + (size_t)lane * 68, wfc_s, u0, acc);
                cell4(acc, cc_r[sg], ch_r[sg]);
                if (lane < cnt) {
                    float* dp = a.chg + (size_t)(c0 + r0 + lane) * 64 + u0;
                    stg_sc2(dp,     ch_r[sg][0], ch_r[sg][1]);
                    stg_sc2(dp + 2, ch_r[sg][2], ch_r[sg][3]);
                }
                __syncthreads();   // LM reads complete before next subgroup's gather
            }
            bar_arrive(barg, 2 * step);    // S2 arrive (chg written); clause skips S2 wait
            if (step < STEPS_ - 1) {
                // precompute ch(step) @ cwhh for next step while lit does slot2
#pragma unroll 1
                for (int sg = 0; sg < 3; ++sg) {
                    *(float4*)(LM + (size_t)lane * 68 + u0) =
                        make_float4(ch_r[sg][0], ch_r[sg][1], ch_r[sg][2], ch_r[sg][3]);
                    __syncthreads();
#pragma unroll
                    for (int i = 0; i < 16; ++i) acc2[sg][i] = 0.f;
                    gemm16<256, 64>(LM + (size_t)lane * 68, cwhh_s, u0, acc2[sg]);
                    __syncthreads();
                }
                bar_arrive(barg, 2 * step + 1);    // S1 arrive
                bar_wait(barg, 2 * step + 1);      // S1 wait: out_g(step+1) ready
            }
        }
    }
}

// ---------------- host ----------------

extern "C" void kernel_launch(void* const* d_in, const int* in_sizes, int n_in,
                              void* d_out, int out_size, void* d_ws, size_t ws_size,
                              hipStream_t stream)
{
    (void)in_sizes; (void)n_in; (void)out_size; (void)ws_size;
    const float* x    = (const float*)d_in[0];
    const int*   ei   = (const int*)d_in[2];
    const float* liw  = (const float*)d_in[4];
    const float* lib  = (const float*)d_in[5];
    const float* ciw  = (const float*)d_in[6];
    const float* cib  = (const float*)d_in[7];
    const float* lm1  = (const float*)d_in[8];
    const float* lm1b = (const float*)d_in[9];
    const float* lm2  = (const float*)d_in[10];
    const float* lm2b = (const float*)d_in[11];
    const float* lm3  = (const float*)d_in[12];
    const float* lm3b = (const float*)d_in[13];
    const float* cm1  = (const float*)d_in[14];
    const float* cm1b = (const float*)d_in[15];
    const float* cm2  = (const float*)d_in[16];
    const float* cm2b = (const float*)d_in[17];
    const float* cm3  = (const float*)d_in[18];
    const float* cm3b = (const float*)d_in[19];
    const float* lu_wih = (const float*)d_in[20];
    const float* lu_whh = (const float*)d_in[21];
    const float* lu_bih = (const float*)d_in[22];
    const float* lu_bhh = (const float*)d_in[23];
    const float* cu_wih = (const float*)d_in[24];
    const float* cu_whh = (const float*)d_in[25];
    const float* cu_bih = (const float*)d_in[26];
    const float* cu_bhh = (const float*)d_in[27];
    const float* lv1  = (const float*)d_in[28];
    const float* lv1b = (const float*)d_in[29];
    const float* lv2  = (const float*)d_in[30];
    const float* lv2b = (const float*)d_in[31];
    const float* lv3  = (const float*)d_in[32];
    const float* lv3b = (const float*)d_in[33];

    float* F = (float*)d_ws;
    size_t o = 0;
    auto A = [&](size_t n) { float* p = F + o; o += n; return p; };
    float* out_g = A((size_t)NLIT_ * 64);
    float* outc0 = A((size_t)NCLS_ * 64);
    float* chg   = A((size_t)NCLS_ * 64);
    float* Wl    = A(4096);
    float* Wc    = A(4096);
    float* bl    = A(64);
    float* bc    = A(64);
    float* Wv    = A(64);
    float* bv    = A(16);
    float* Wfl   = A(64 * 256);
    float* bfl   = A(256);
    float* Bl    = A(256);
    float* Wfc   = A(64 * 256);
    float* Bc    = A(256);
    int* I = (int*)(F + o);
    int* llits  = I; I += NE_;
    int* rowptr = I; I += 12804;
    int* cursor = I; I += NLIT_;
    int* colA   = I; I += NE_;
    int* cnt    = I; I += NLIT_;
    int* bar    = I; I += GRP_ * 48 * PHSTR_;

    hipMemsetAsync(cnt, 0, NLIT_ * sizeof(int), stream);
    hipMemsetAsync(bar, 0, GRP_ * 48 * PHSTR_ * sizeof(int), stream);
    hipMemsetAsync(d_out, 0, (size_t)NN_ * sizeof(float), stream);

    collapse_k<<<3, 256, 0, stream>>>(lm1, lm1b, lm2, lm2b, lm3, lm3b,
                                      cm1, cm1b, cm2, cm2b, cm3, cm3b,
                                      lv1, lv1b, lv2, lv2b, lv3, lv3b,
                                      Wl, bl, Wc, bc, Wv, bv);
    fold_k<<<2, 256, 0, stream>>>(Wl, bl, Wc, bc,
                                  lu_wih, lu_bih, lu_bhh,
                                  cu_wih, cu_bih, cu_bhh,
                                  Wfl, bfl, Bl, Wfc, Bc);
    init_k<<<(NN_ * 64 + 255) / 256, 256, 0, stream>>>(x, liw, lib, ciw, cib, out_g, outc0);
    econv_k<<<NE_ / 256, 256, 0, stream>>>(ei, llits, cnt);
    scan_k<<<1, 1024, 0, stream>>>(cnt, rowptr, cursor);
    fill_k<<<NE_ / 256, 256, 0, stream>>>(llits, cursor, colA);

    KArgs ka;
    ka.out_g = out_g; ka.outc0 = outc0; ka.chg = chg;
    ka.llits = llits; ka.rowptr = rowptr; ka.col = colA;
    ka.Wfl = Wfl; ka.bfl = bfl; ka.Bl = Bl; ka.Wfc = Wfc; ka.Bc = Bc;
    ka.lwih = lu_wih; ka.lwhh = lu_whh; ka.cwhh = cu_whh;
    ka.Wv = Wv; ka.bv = bv;
    ka.vout = (float*)d_out;
    ka.bar = bar;

    void* params[] = { &ka };
    hipError_t err = hipLaunchCooperativeKernel((void*)fused_k, dim3(NBLK_), dim3(1024),
                                                params, SMEM_BYTES, stream);
    if (err != hipSuccess) {
        fused_k<<<NBLK_, 1024, SMEM_BYTES, stream>>>(ka);
    }
}